// Round 8
// baseline (241.295 us; speedup 1.0000x reference)
//
#include <hip/hip_runtime.h>

// Problem constants (match reference)
constexpr int BB  = 8;
constexpr int NN  = 2048;
constexpr int IND = 128;
constexpr int HD  = 64;
constexpr float LN_EPS = 1e-5f;
constexpr float SLOPE  = 0.2f;

typedef _Float16 half8 __attribute__((ext_vector_type(8)));
typedef _Float16 half4 __attribute__((ext_vector_type(4)));
typedef float    f32x4 __attribute__((ext_vector_type(4)));

__device__ __forceinline__ float wave_sum(float v) {
    #pragma unroll
    for (int off = 32; off > 0; off >>= 1) v += __shfl_xor(v, off);
    return v;
}
__device__ __forceinline__ float wave_max(float v) {
    #pragma unroll
    for (int off = 32; off > 0; off >>= 1) v = fmaxf(v, __shfl_xor(v, off));
    return v;
}

// ---------------------------------------------------------------------------
// Kernel 0 (unchanged): build Wt[256 cols][192 k] fp16, k-major.
//   [0,64): r-gate  [64,128): i-gate  [128,192): i_n (x only)  [192,256): h_n (h only)
// ---------------------------------------------------------------------------
__global__ void k_prep(const float* __restrict__ X2H, const float* __restrict__ H2H,
                       _Float16* __restrict__ Wt)
{
    const int tot = 256 * 192;
    for (int idx = blockIdx.x * 256 + threadIdx.x; idx < tot; idx += gridDim.x * 256) {
        const int col = idx / 192, k = idx % 192;
        float v;
        if (col < 128)       v = (k < 128) ? X2H[(size_t)k * 192 + col]
                                           : H2H[(size_t)(k - 128) * 192 + col];
        else if (col < 192)  v = (k < 128) ? X2H[(size_t)k * 192 + col] : 0.f;
        else                 v = (k >= 128) ? H2H[(size_t)(k - 128) * 192 + (col - 64)] : 0.f;
        Wt[idx] = (_Float16)v;
    }
}

// ---------------------------------------------------------------------------
// Kernel 1 (unchanged from R6): gates via fp16 MFMA, 16 rows x 4 waves.
// ---------------------------------------------------------------------------
__global__ __launch_bounds__(256, 4) void k_gates(
    const float* __restrict__ x, const float* __restrict__ h,
    const _Float16* __restrict__ Wt, const float* __restrict__ a,
    float* __restrict__ Wh_out, _Float16* __restrict__ Whh2,
    float* __restrict__ Wh1, float* __restrict__ Wh2)
{
    __shared__ float gbuf[16][260];

    const int tid = threadIdx.x, lane = tid & 63, w = tid >> 6;
    const int m = lane & 15, q = lane >> 4;
    const int row0 = blockIdx.x * 16;

    f32x4 acc[4];
    #pragma unroll
    for (int ct = 0; ct < 4; ++ct) acc[ct] = (f32x4){0.f, 0.f, 0.f, 0.f};

    #pragma unroll
    for (int kc = 0; kc < 6; ++kc) {
        half8 a8;
        if (kc < 4) {
            const float* xp = x + (size_t)(row0 + m) * IND + kc * 32 + q * 8;
            const f32x4 v0 = *(const f32x4*)xp;
            const f32x4 v1 = *(const f32x4*)(xp + 4);
            #pragma unroll
            for (int j = 0; j < 4; ++j) { a8[j] = (_Float16)v0[j]; a8[4 + j] = (_Float16)v1[j]; }
        } else {
            const float* hp_ = h + (size_t)(row0 + m) * HD + (kc - 4) * 32 + q * 8;
            const f32x4 v0 = *(const f32x4*)hp_;
            const f32x4 v1 = *(const f32x4*)(hp_ + 4);
            #pragma unroll
            for (int j = 0; j < 4; ++j) { a8[j] = (_Float16)v0[j]; a8[4 + j] = (_Float16)v1[j]; }
        }
        #pragma unroll
        for (int ct = 0; ct < 4; ++ct) {
            const half8 b8 = *(const half8*)(Wt + ((size_t)(w * 64 + ct * 16 + m) * 192 + kc * 32 + q * 8));
            acc[ct] = __builtin_amdgcn_mfma_f32_16x16x32_f16(a8, b8, acc[ct], 0, 0, 0);
        }
    }

    #pragma unroll
    for (int ct = 0; ct < 4; ++ct)
        #pragma unroll
        for (int r2 = 0; r2 < 4; ++r2)
            gbuf[q * 4 + r2][w * 64 + ct * 16 + m] = acc[ct][r2];
    __syncthreads();

    const float a0 = a[lane], a1 = a[64 + lane];
    half4 p4;
    const int grow0 = row0 + w * 4;
    #pragma unroll
    for (int r = 0; r < 4; ++r) {
        const int row = w * 4 + r;
        const int grow = row0 + row;
        const float g0 = gbuf[row][lane];
        const float g1 = gbuf[row][64 + lane];
        const float g2 = gbuf[row][128 + lane];
        const float g3 = gbuf[row][192 + lane];
        const float rg = 1.f / (1.f + __expf(-g0));
        const float ig = 1.f / (1.f + __expf(-g1));
        const float irh = g2 + rg * g3;
        const float mu = wave_sum(irh) * (1.f / 64.f);
        const float dv = irh - mu;
        const float var = wave_sum(dv * dv) * (1.f / 64.f);
        const float ng = tanhf(dv * rsqrtf(var + LN_EPS));
        const float hr = h[(size_t)grow * HD + lane];
        const float wh = ng + ig * (hr - ng);
        Wh_out[(size_t)grow * HD + lane] = wh;
        p4[r] = (_Float16)wh;
        const float d1 = wave_sum(wh * a0);
        const float d2 = wave_sum(wh * a1);
        if (lane == 0) { Wh1[grow] = d1; Wh2[grow] = d2; }
    }
    *(half4*)(Whh2 + ((size_t)(grow0 >> 3) * 64 + lane) * 8 + (w & 1) * 4) = p4;
}

// ---------------------------------------------------------------------------
// Kernel 2: attention.  Block = 512 threads (8 waves) x 16 query rows; wave w
// owns K-chunk w end-to-end.  NO inner barriers: each wave free-runs its
// stream->score->MFMA pipeline (P slice is wave-private; same-wave DS
// ordering + compiler lgkmcnt make write->read safe).  Row sums come from a
// 5th MFMA chain with B = ones (replaces 96 ds_bpermute per wave).
// Barriers: 1 for batch-max M, 1 before the LDS-aliasing partial combine.
// ---------------------------------------------------------------------------
constexpr int KC  = 256;
constexpr int PST = KC + 8;    // 264

__global__ __launch_bounds__(512, 4) void k_attn(
    const int* __restrict__ adj,
    const _Float16* __restrict__ Whh2,   // [B][N/8][64][8]
    const float* __restrict__ Wh1, const float* __restrict__ Wh2,
    float* __restrict__ hp)
{
    __shared__ __align__(16) _Float16 Pall[8 * 16 * PST];   // 67584 B
    __shared__ float ssum[8][16];
    __shared__ float redb[8];

    const int tid  = threadIdx.x;
    const int lane = tid & 63;
    const int w    = tid >> 6;               // wave id = chunk id (0..7)
    const int b    = blockIdx.x >> 7;
    const int i0   = (blockIdx.x & 127) * 16;
    const int m    = lane & 15;
    const int q    = lane >> 4;

    _Float16* __restrict__ Pw = Pall + w * 16 * PST;

    // Wh2 cache for this wave's chunk: cols w*256 + 4*lane + d
    const f32x4 wv = ((const f32x4*)(Wh2 + (size_t)b * NN))[w * 64 + lane];

    // batch-wide max of Wh2 (8 waves cover all 2048)
    float mx = fmaxf(fmaxf(wv[0], wv[1]), fmaxf(wv[2], wv[3]));
    mx = wave_max(mx);
    if (lane == 0) redb[w] = mx;
    __syncthreads();
    float M = redb[0];
    #pragma unroll
    for (int i = 1; i < 8; ++i) M = fmaxf(M, redb[i]);

    float w1r[16];
    #pragma unroll
    for (int r = 0; r < 16; ++r) w1r[r] = Wh1[b * NN + i0 + r];

    // adj: row r of this tile, this wave's chunk, this lane's 4 cols
    const int* __restrict__ abase = adj + ((size_t)b * NN + i0) * NN + w * KC + 4 * lane;

    // ---- Phase A: double-buffered adj stream -> P slice (no barriers) ----
    int4 buf0[4], buf1[4];
    #pragma unroll
    for (int r = 0; r < 4; ++r) buf0[r] = *(const int4*)(abase + (size_t)r * NN);
    #pragma unroll
    for (int r = 0; r < 4; ++r) buf1[r] = *(const int4*)(abase + (size_t)(4 + r) * NN);

    #pragma unroll
    for (int g = 0; g < 4; ++g) {
        #pragma unroll
        for (int rr = 0; rr < 4; ++rr) {
            const int r = g * 4 + rr;
            const int4 av = (g & 1) ? buf1[rr] : buf0[rr];
            const int ai[4] = {av.x, av.y, av.z, av.w};
            const float t0 = w1r[r] + M;
            const float c  = (t0 > 0.f) ? t0 : SLOPE * t0;   // exact row upper bound
            half4 ph;
            #pragma unroll
            for (int d = 0; d < 4; ++d) {
                const float t = w1r[r] + wv[d];
                const float e = (t > 0.f) ? t : SLOPE * t;
                const float p = ai[d] ? __expf(e - c) : 0.f;
                ph[d] = (_Float16)p;
            }
            *(half4*)&Pw[r * PST + 4 * lane] = ph;           // ds_write_b64
        }
        if (g + 2 < 4) {
            #pragma unroll
            for (int rr = 0; rr < 4; ++rr) {
                int4 nv = *(const int4*)(abase + (size_t)((g + 2) * 4 + rr) * NN);
                if (g & 1) buf1[rr] = nv; else buf0[rr] = nv;
            }
        }
    }
    __builtin_amdgcn_wave_barrier();   // scheduling fence only (zero-cost)

    // ---- Phase B: partial 16x64 += P_w @ Wh[chunk w]; 5th chain = row sums
    const half8* __restrict__ Wp = (const half8*)(Whh2 + (size_t)b * NN * HD);
    const half8 ones = {(_Float16)1.f, (_Float16)1.f, (_Float16)1.f, (_Float16)1.f,
                        (_Float16)1.f, (_Float16)1.f, (_Float16)1.f, (_Float16)1.f};
    f32x4 acc[4];
    #pragma unroll
    for (int cc = 0; cc < 4; ++cc) acc[cc] = (f32x4){0.f, 0.f, 0.f, 0.f};
    f32x4 acc1 = (f32x4){0.f, 0.f, 0.f, 0.f};

    #pragma unroll
    for (int k8 = 0; k8 < 8; ++k8) {
        const half8 a8 = *(const half8*)&Pw[m * PST + k8 * 32 + q * 8];
        #pragma unroll
        for (int cc = 0; cc < 4; ++cc) {
            const half8 b8 = Wp[(size_t)(w * 32 + k8 * 4 + q) * 64 + cc * 16 + m];
            acc[cc] = __builtin_amdgcn_mfma_f32_16x16x32_f16(a8, b8, acc[cc], 0, 0, 0);
        }
        acc1 = __builtin_amdgcn_mfma_f32_16x16x32_f16(a8, ones, acc1, 0, 0, 0);
    }
    // row sums: D[row=q*4+r2][col=m], all cols equal
    if (m == 0) {
        #pragma unroll
        for (int r2 = 0; r2 < 4; ++r2) ssum[w][q * 4 + r2] = acc1[r2];
    }
    __syncthreads();   // all Phase-B ds_reads done before aliasing P region

    // ---- 8-way partial combine (alias dead P region, stride-17 pad) ----
    float* __restrict__ accb = (float*)Pall;
    #pragma unroll
    for (int cc = 0; cc < 4; ++cc)
        *(f32x4*)&accb[(w * 64 + lane) * 17 + cc * 4] = acc[cc];
    __syncthreads();

    if (w < 4) {
        f32x4 tot = (f32x4){0.f, 0.f, 0.f, 0.f};
        #pragma unroll
        for (int wp = 0; wp < 8; ++wp) {
            const f32x4 t4 = *(const f32x4*)&accb[(wp * 64 + lane) * 17 + w * 4];
            tot[0] += t4[0]; tot[1] += t4[1]; tot[2] += t4[2]; tot[3] += t4[3];
        }
        #pragma unroll
        for (int r2 = 0; r2 < 4; ++r2) {
            const int irow = q * 4 + r2;
            float S = 0.f;
            #pragma unroll
            for (int wp = 0; wp < 8; ++wp) S += ssum[wp][irow];
            hp[((size_t)b * NN + i0 + irow) * HD + w * 16 + m] = tot[r2] / S;
        }
    }
}

// ---------------------------------------------------------------------------
extern "C" void kernel_launch(void* const* d_in, const int* in_sizes, int n_in,
                              void* d_out, int out_size, void* d_ws, size_t ws_size,
                              hipStream_t stream) {
    const int*   adj = (const int*)d_in[0];
    const float* x   = (const float*)d_in[1];
    const float* h   = (const float*)d_in[2];
    const float* X2H = (const float*)d_in[3];
    const float* H2H = (const float*)d_in[4];
    const float* a   = (const float*)d_in[5];

    float* out = (float*)d_out;
    float* hp  = out;                              // h_prime [8][2048][64]
    float* Wh  = out + (size_t)BB * NN * HD;       // Wh      [8][2048][64]

    float*    Wh1  = (float*)d_ws;                           // [B*N]
    float*    Wh2  = Wh1 + BB * NN;                          // [B*N]
    _Float16* Whh2 = (_Float16*)(Wh2 + BB * NN);             // [B][N/8][64][8]
    _Float16* Wt   = Whh2 + (size_t)BB * NN * HD;            // [256][192]

    k_prep<<<dim3(64), dim3(256), 0, stream>>>(X2H, H2H, Wt);
    k_gates<<<dim3((BB * NN) / 16), dim3(256), 0, stream>>>(
        x, h, Wt, a, Wh, Whh2, Wh1, Wh2);
    k_attn<<<dim3(BB * (NN / 16)), dim3(512), 0, stream>>>(
        adj, Whh2, Wh1, Wh2, hp);
}